// Round 5
// baseline (370.545 us; speedup 1.0000x reference)
//
#include <hip/hip_runtime.h>

#define B_ 64
#define T_ 2048
#define E_ 256
#define U_ 256
#define O_ 32000
#define UE_ 512

typedef __attribute__((ext_vector_type(8))) short bf16x8;
typedef __attribute__((ext_vector_type(4))) float f32x4;

__device__ __forceinline__ unsigned short f2bf(float f){
  unsigned u = __builtin_bit_cast(unsigned, f);
  u = u + 0x7FFFu + ((u >> 16) & 1u);
  return (unsigned short)(u >> 16);
}
__device__ __forceinline__ unsigned pk2bf(float a, float b){
  return (unsigned)f2bf(a) | ((unsigned)f2bf(b) << 16);
}
__device__ __forceinline__ bf16x8 pack8(const float* v0, const float* v1){
  float4 x = *(const float4*)v0;
  float4 y = *(const float4*)v1;
  uint4 pk;
  pk.x = pk2bf(x.x, x.y); pk.y = pk2bf(x.z, x.w);
  pk.z = pk2bf(y.x, y.y); pk.w = pk2bf(y.z, y.w);
  return __builtin_bit_cast(bf16x8, pk);
}
__device__ __forceinline__ float ftanh(float x){
  float e = __expf(2.0f*x);
  return 1.0f - 2.0f/(e + 1.0f);
}
__device__ __forceinline__ float fsig(float x){
  return 1.0f/(1.0f + __expf(-x));
}

// ---------------- K0a: pack W_a[256:512, :] into bf16 MFMA-fragment layout ----------------
// bpack[((ks*4+g)*512 + n)*8 + i] = bf16( W_a[(256 + ks*32 + g*8 + i)*512 + n] )
__global__ void pack_b_kernel(const float* __restrict__ Wa, unsigned short* __restrict__ bpack){
  int idx = blockIdx.x*256 + threadIdx.x;      // 16384 = 32 ktg * 512 n
  int n = idx & 511;
  int ktg = idx >> 9;
  int erow = ktg * 8;
  unsigned short o[8];
#pragma unroll
  for (int i = 0; i < 8; ++i)
    o[i] = f2bf(Wa[(256 + erow + i)*512 + n]);
  uint4 v;
  v.x = (unsigned)o[0] | ((unsigned)o[1] << 16);
  v.y = (unsigned)o[2] | ((unsigned)o[3] << 16);
  v.z = (unsigned)o[4] | ((unsigned)o[5] << 16);
  v.w = (unsigned)o[6] | ((unsigned)o[7] << 16);
  ((uint4*)bpack)[idx] = v;
}

// ---------------- K0b (MFMA): sp[b][n] = sum_u stm[b][u] * W_a[u][n], n in [0,512) ----------------
__global__ __launch_bounds__(256)
void stmpart_mfma_kernel(const float* __restrict__ stm, const float* __restrict__ Wa,
                         float* __restrict__ sp){
  int tid = threadIdx.x;
  int w = tid >> 6, l = tid & 63, c = l & 15, g = l >> 4;
  int n0 = blockIdx.x*64 + w*16;        // 8 blocks -> 512 cols
  f32x4 zero = {0.f,0.f,0.f,0.f};
  f32x4 acc[4];
#pragma unroll
  for (int mt = 0; mt < 4; ++mt) acc[mt] = zero;
#pragma unroll
  for (int ks = 0; ks < 8; ++ks){
    int kg = ks*32 + 8*g;
    bf16x8 a[4];
#pragma unroll
    for (int mt = 0; mt < 4; ++mt){
      const float* ap = stm + (mt*16 + c)*256 + kg;
      a[mt] = pack8(ap, ap + 4);
    }
    const float* bpt = Wa + (size_t)kg*512 + n0 + c;
    float bv[8];
#pragma unroll
    for (int i = 0; i < 8; ++i) bv[i] = bpt[(size_t)i*512];
    uint4 pk;
    pk.x = pk2bf(bv[0], bv[1]); pk.y = pk2bf(bv[2], bv[3]);
    pk.z = pk2bf(bv[4], bv[5]); pk.w = pk2bf(bv[6], bv[7]);
    bf16x8 bfr = __builtin_bit_cast(bf16x8, pk);
#pragma unroll
    for (int mt = 0; mt < 4; ++mt)
      acc[mt] = __builtin_amdgcn_mfma_f32_16x16x32_bf16(a[mt], bfr, acc[mt], 0, 0, 0);
  }
#pragma unroll
  for (int mt = 0; mt < 4; ++mt)
#pragma unroll
    for (int r = 0; r < 4; ++r){
      int m = mt*16 + 4*g + r;
      sp[m*512 + n0 + c] = acc[mt][r];
    }
}

// ---------------- K1 v3: fused et GEMM ----------------
// 1024 blocks x 512 threads; 2 tiles of 64 rows x 512 cols per block.
// LDS A-tile fragment-contiguous with XOR bank swizzle:
//   logical uint4 slot s = ((mt*8+ks)*64 + g*16 + c), physical = s ^ ((s>>4)&7)
// Tile-1 global loads issued before tile-0 compute (reg prefetch).
__global__ __launch_bounds__(512, 3)
void et3_kernel(const float* __restrict__ xseq, const unsigned short* __restrict__ bpack,
                const float* __restrict__ va, const float* __restrict__ sp,
                float* __restrict__ et){
  __shared__ __align__(16) uint4 sA4[2048];   // 32KB
  __shared__ float sEt[8][64];
  int tid = threadIdx.x;
  int w = tid >> 6, l = tid & 63, c = l & 15, g = l >> 4;
  int b = blockIdx.x >> 4;                 // 16 blocks (128 rows each) per batch b

  float va_r[4], sp_r[4];
#pragma unroll
  for (int nt = 0; nt < 4; ++nt){
    int n = w*64 + nt*16 + c;
    va_r[nt] = va[n];
    sp_r[nt] = sp[b*512 + n];
  }

  // staging geometry: thread owns row r (0..63), octet-phase jb (0..7); octets j = jb+8i
  int r = tid >> 3, jb = tid & 7;
  const float4* x4 = (const float4*)xseq;
  const bf16x8* bp = (const bf16x8*)bpack;

  float4 f[8];
  {  // load tile 0
    size_t fb = ((size_t)(blockIdx.x*128 + r))*64 + jb*2;
#pragma unroll
    for (int i = 0; i < 4; ++i){ f[2*i] = x4[fb + 16*i]; f[2*i+1] = x4[fb + 16*i + 1]; }
  }

  for (int t = 0; t < 2; ++t){
    int m0 = blockIdx.x*128 + t*64;

    // stage regs -> LDS (swizzled)
#pragma unroll
    for (int i = 0; i < 4; ++i){
      int j = jb + 8*i;
      int s = ((r>>4)*8 + (j>>2))*64 + (j&3)*16 + (r&15);
      uint4 pk;
      pk.x = pk2bf(f[2*i].x,   f[2*i].y);   pk.y = pk2bf(f[2*i].z,   f[2*i].w);
      pk.z = pk2bf(f[2*i+1].x, f[2*i+1].y); pk.w = pk2bf(f[2*i+1].z, f[2*i+1].w);
      sA4[s ^ ((s>>4)&7)] = pk;
    }
    __syncthreads();

    // prefetch tile 1 while computing tile 0
    if (t == 0){
      size_t fb = ((size_t)(m0 + 64 + r))*64 + jb*2;
#pragma unroll
      for (int i = 0; i < 4; ++i){ f[2*i] = x4[fb + 16*i]; f[2*i+1] = x4[fb + 16*i + 1]; }
    }

    f32x4 zero = {0.f,0.f,0.f,0.f};
    f32x4 acc[4][4];
#pragma unroll
    for (int mt = 0; mt < 4; ++mt)
#pragma unroll
      for (int nt = 0; nt < 4; ++nt) acc[mt][nt] = zero;

#pragma unroll
    for (int ks = 0; ks < 8; ++ks){
      bf16x8 a[4], bb[4];
#pragma unroll
      for (int mt = 0; mt < 4; ++mt){
        int idx = (mt*8 + ks)*64 + l;
        a[mt] = *(const bf16x8*)&sA4[idx ^ ((idx>>4)&7)];
      }
      int bbase = (ks*4 + g)*512 + w*64 + c;
#pragma unroll
      for (int nt = 0; nt < 4; ++nt) bb[nt] = bp[bbase + nt*16];
#pragma unroll
      for (int mt = 0; mt < 4; ++mt)
#pragma unroll
        for (int nt = 0; nt < 4; ++nt)
          acc[mt][nt] = __builtin_amdgcn_mfma_f32_16x16x32_bf16(a[mt], bb[nt], acc[mt][nt], 0, 0, 0);
    }

    // epilogue: p[row] = sum_n Va[n]*tanh(S + sp[n]); reduce over 16 c-lanes
    float pr[4][4];
#pragma unroll
    for (int mt = 0; mt < 4; ++mt)
#pragma unroll
      for (int r4 = 0; r4 < 4; ++r4){
        float p = 0.f;
#pragma unroll
        for (int nt = 0; nt < 4; ++nt)
          p += va_r[nt] * ftanh(acc[mt][nt][r4] + sp_r[nt]);
        pr[mt][r4] = p;
      }
#pragma unroll
    for (int mask = 1; mask < 16; mask <<= 1){
#pragma unroll
      for (int mt = 0; mt < 4; ++mt)
#pragma unroll
        for (int r4 = 0; r4 < 4; ++r4)
          pr[mt][r4] += __shfl_xor(pr[mt][r4], mask, 64);
    }
    if (c == 0){
#pragma unroll
      for (int mt = 0; mt < 4; ++mt)
#pragma unroll
        for (int r4 = 0; r4 < 4; ++r4)
          sEt[w][mt*16 + 4*g + r4] = pr[mt][r4];
    }
    __syncthreads();      // sEt done + all LDS-A reads done
    if (tid < 64){
      float e = 0.f;
#pragma unroll
      for (int ww = 0; ww < 8; ++ww) e += sEt[ww][tid];
      et[m0 + tid] = e;
    }
    // next-iter stage writes sA4 only (disjoint from sEt reads) -> no extra barrier
  }
}

// ---------------- K2: softmax over T per b -> at ----------------
__global__ void at_kernel(const float* __restrict__ et, float* __restrict__ at){
  __shared__ float red[4];
  __shared__ float red2[4];
  int b = blockIdx.x, tid = threadIdx.x;
  float v[8];
#pragma unroll
  for (int i = 0; i < 8; ++i) v[i] = et[b*2048 + i*256 + tid];
  float m = v[0];
#pragma unroll
  for (int i = 1; i < 8; ++i) m = fmaxf(m, v[i]);
#pragma unroll
  for (int off = 1; off < 64; off <<= 1) m = fmaxf(m, __shfl_xor(m, off, 64));
  int wv = tid >> 6;
  if ((tid & 63) == 0) red[wv] = m;
  __syncthreads();
  m = fmaxf(fmaxf(red[0], red[1]), fmaxf(red[2], red[3]));
  float e[8]; float s = 0.f;
#pragma unroll
  for (int i = 0; i < 8; ++i){ e[i] = __expf(v[i] - m); s += e[i]; }
#pragma unroll
  for (int off = 1; off < 64; off <<= 1) s += __shfl_xor(s, off, 64);
  if ((tid & 63) == 0) red2[wv] = s;
  __syncthreads();
  s = red2[0] + red2[1] + red2[2] + red2[3];
  float inv = 1.0f / s;
#pragma unroll
  for (int i = 0; i < 8; ++i) at[b*2048 + i*256 + tid] = e[i] * inv;
}

// ---------------- K3: context partials over T chunks ----------------
__global__ void ctxpart_kernel(const float* __restrict__ at, const float* __restrict__ xseq,
                               float* __restrict__ cp){
  __shared__ float s_at[256];
  int ch = blockIdx.x;
  int b  = blockIdx.y;
  int e  = threadIdx.x;
  int t0 = ch * 256;
  s_at[e] = at[b*2048 + t0 + e];
  __syncthreads();
  float acc = 0.f;
  const float* xp = xseq + ((size_t)(b*2048 + t0))*256 + e;
#pragma unroll 4
  for (int tt = 0; tt < 256; ++tt)
    acc += s_at[tt] * xp[(size_t)tt * 256];
  cp[(b*8 + ch)*256 + e] = acc;
}

// ---------------- K4: reduce context + build X1bf = bf16([inputs | stm | ctx]) ----------------
__global__ void ctx_x1_kernel(const float* __restrict__ cp, const float* __restrict__ inputs,
                              const float* __restrict__ stm,
                              unsigned short* __restrict__ X1bf){
  int b = blockIdx.x, e = threadIdx.x;
  float s = 0.f;
#pragma unroll
  for (int c = 0; c < 8; ++c) s += cp[(b*8 + c)*256 + e];
  X1bf[b*768 + e]        = f2bf(inputs[b*256 + e]);
  X1bf[b*768 + 256 + e]  = f2bf(stm[b*256 + e]);
  X1bf[b*768 + 512 + e]  = f2bf(s);
}

// ---------------- K5a: gate preactivations r,z + p_ic via MFMA ----------------
__global__ __launch_bounds__(256)
void gates1_kernel(const unsigned short* __restrict__ X1bf, const float* __restrict__ stm,
                   const float* __restrict__ Wr, const float* __restrict__ Ur,
                   const float* __restrict__ Cr, const float* __restrict__ brr,
                   const float* __restrict__ Wz, const float* __restrict__ Uz,
                   const float* __restrict__ Cz, const float* __restrict__ bzz,
                   const float* __restrict__ Wp, const float* __restrict__ Cp,
                   const float* __restrict__ bpp,
                   float* __restrict__ rs, float* __restrict__ ztb, float* __restrict__ pic){
  int tid = threadIdx.x;
  int w = tid >> 6, l = tid & 63, c = l & 15, g = l >> 4;
  int n0 = blockIdx.x*64 + w*16;          // 12 blocks -> 768 cols
  int gate = n0 >> 8;
  int col0 = n0 & 255;
  const float* W0; const float* W1; const float* W2; const float* bias;
  if (gate == 0){ W0 = Wr; W1 = Ur; W2 = Cr; bias = brr; }
  else if (gate == 1){ W0 = Wz; W1 = Uz; W2 = Cz; bias = bzz; }
  else { W0 = Wp; W1 = nullptr; W2 = Cp; bias = bpp; }

  f32x4 zero = {0.f,0.f,0.f,0.f};
  f32x4 acc[4];
#pragma unroll
  for (int mt = 0; mt < 4; ++mt) acc[mt] = zero;

#pragma unroll
  for (int ph = 0; ph < 3; ++ph){
    const float* src = (ph == 0) ? W0 : (ph == 1) ? W1 : W2;
    if (src == nullptr) continue;
#pragma unroll
    for (int ks = 0; ks < 8; ++ks){
      int kg = ks*32 + 8*g;
      bf16x8 a[4];
#pragma unroll
      for (int mt = 0; mt < 4; ++mt)
        a[mt] = *(const bf16x8*)&X1bf[(mt*16 + c)*768 + ph*256 + kg];
      const float* bpt = src + (size_t)kg*256 + col0 + c;
      float bv[8];
#pragma unroll
      for (int i = 0; i < 8; ++i) bv[i] = bpt[(size_t)i*256];
      uint4 pk;
      pk.x = pk2bf(bv[0], bv[1]); pk.y = pk2bf(bv[2], bv[3]);
      pk.z = pk2bf(bv[4], bv[5]); pk.w = pk2bf(bv[6], bv[7]);
      bf16x8 bfr = __builtin_bit_cast(bf16x8, pk);
#pragma unroll
      for (int mt = 0; mt < 4; ++mt)
        acc[mt] = __builtin_amdgcn_mfma_f32_16x16x32_bf16(a[mt], bfr, acc[mt], 0, 0, 0);
    }
  }

  int n = col0 + c;
  float bi = bias[n];
#pragma unroll
  for (int mt = 0; mt < 4; ++mt)
#pragma unroll
    for (int r = 0; r < 4; ++r){
      int m = mt*16 + 4*g + r;
      float pre = acc[mt][r] + bi;
      if (gate == 0)      rs[m*256 + n]  = fsig(pre) * stm[m*256 + n];
      else if (gate == 1) ztb[m*256 + n] = fsig(pre);
      else                pic[m*256 + n] = pre;
    }
}

// ---------------- K5b: st = (1-z)*stm + z*tanh(pic + rs@Up) ----------------
__global__ __launch_bounds__(256)
void gates2_kernel(const float* __restrict__ rs, const float* __restrict__ Up,
                   const float* __restrict__ pic, const float* __restrict__ ztb,
                   const float* __restrict__ stm, float* __restrict__ stout){
  int tid = threadIdx.x;
  int w = tid >> 6, l = tid & 63, c = l & 15, g = l >> 4;
  int n0 = blockIdx.x*64 + w*16;          // 4 blocks -> 256 cols
  f32x4 zero = {0.f,0.f,0.f,0.f};
  f32x4 acc[4];
#pragma unroll
  for (int mt = 0; mt < 4; ++mt) acc[mt] = zero;
#pragma unroll
  for (int ks = 0; ks < 8; ++ks){
    int kg = ks*32 + 8*g;
    bf16x8 a[4];
#pragma unroll
    for (int mt = 0; mt < 4; ++mt){
      const float* ap = rs + (mt*16 + c)*256 + kg;
      a[mt] = pack8(ap, ap + 4);
    }
    const float* bpt = Up + (size_t)kg*256 + n0 + c;
    float bv[8];
#pragma unroll
    for (int i = 0; i < 8; ++i) bv[i] = bpt[(size_t)i*256];
    uint4 pk;
    pk.x = pk2bf(bv[0], bv[1]); pk.y = pk2bf(bv[2], bv[3]);
    pk.z = pk2bf(bv[4], bv[5]); pk.w = pk2bf(bv[6], bv[7]);
    bf16x8 bfr = __builtin_bit_cast(bf16x8, pk);
#pragma unroll
    for (int mt = 0; mt < 4; ++mt)
      acc[mt] = __builtin_amdgcn_mfma_f32_16x16x32_bf16(a[mt], bfr, acc[mt], 0, 0, 0);
  }
#pragma unroll
  for (int mt = 0; mt < 4; ++mt)
#pragma unroll
    for (int r = 0; r < 4; ++r){
      int m = mt*16 + 4*g + r;
      int o = m*256 + n0 + c;
      float ap = pic[o] + acc[mt][r];
      float z = ztb[o];
      stout[o] = (1.f - z)*stm[o] + z*ftanh(ap);
    }
}

// ---------------- K6: logits via MFMA, weights converted fp32->bf16 on the fly ----------------
__global__ __launch_bounds__(256)
void logits_mfma_kernel(const unsigned short* __restrict__ X1bf,
                        const float* __restrict__ Wo, const float* __restrict__ Uo,
                        const float* __restrict__ Co, const float* __restrict__ boo,
                        float* __restrict__ outl){
  int tid = threadIdx.x;
  int w = tid >> 6, l = tid & 63, c = l & 15, g = l >> 4;
  int n0 = blockIdx.x*64 + w*16;
  f32x4 zero = {0.f,0.f,0.f,0.f};
  f32x4 acc[4];
#pragma unroll
  for (int mt = 0; mt < 4; ++mt) acc[mt] = zero;

#pragma unroll
  for (int ph = 0; ph < 3; ++ph){
    const float* src = (ph == 0) ? Wo : (ph == 1) ? Uo : Co;
#pragma unroll 2
    for (int ks = 0; ks < 8; ++ks){
      int kg = ph*256 + ks*32 + 8*g;
      bf16x8 a[4];
#pragma unroll
      for (int mt = 0; mt < 4; ++mt)
        a[mt] = *(const bf16x8*)&X1bf[(mt*16 + c)*768 + kg];
      const float* bpt = src + (size_t)(ks*32 + 8*g)*32000 + n0 + c;
      float bv[8];
#pragma unroll
      for (int i = 0; i < 8; ++i) bv[i] = bpt[(size_t)i*32000];
      uint4 pk;
      pk.x = pk2bf(bv[0], bv[1]);
      pk.y = pk2bf(bv[2], bv[3]);
      pk.z = pk2bf(bv[4], bv[5]);
      pk.w = pk2bf(bv[6], bv[7]);
      bf16x8 bfr = __builtin_bit_cast(bf16x8, pk);
#pragma unroll
      for (int mt = 0; mt < 4; ++mt)
        acc[mt] = __builtin_amdgcn_mfma_f32_16x16x32_bf16(a[mt], bfr, acc[mt], 0, 0, 0);
    }
  }

  float bias = boo[n0 + c];
#pragma unroll
  for (int mt = 0; mt < 4; ++mt)
#pragma unroll
    for (int r = 0; r < 4; ++r){
      int m = mt*16 + 4*g + r;
      outl[(size_t)m*32000 + n0 + c] = acc[mt][r] + bias;
    }
}

// ---------------- K7a: per-(b,chunk) (max, sumexp) partials ----------------
__global__ void sm_part_kernel(const float* __restrict__ logits, float* __restrict__ part){
  __shared__ float red[4];
  __shared__ float red2[4];
  int bid = blockIdx.x;           // 512 = 64 b * 8 chunks
  int b = bid >> 3, ch = bid & 7;
  int base = b*32000 + ch*4000;
  int tid = threadIdx.x;
  float v[16];
#pragma unroll
  for (int i = 0; i < 16; ++i){
    int idx = i*256 + tid;
    v[i] = (idx < 4000) ? logits[base + idx] : -INFINITY;
  }
  float m = v[0];
#pragma unroll
  for (int i = 1; i < 16; ++i) m = fmaxf(m, v[i]);
#pragma unroll
  for (int off = 1; off < 64; off <<= 1) m = fmaxf(m, __shfl_xor(m, off, 64));
  int wv = tid >> 6;
  if ((tid & 63) == 0) red[wv] = m;
  __syncthreads();
  m = fmaxf(fmaxf(red[0], red[1]), fmaxf(red[2], red[3]));
  float s = 0.f;
#pragma unroll
  for (int i = 0; i < 16; ++i) s += __expf(v[i] - m);
#pragma unroll
  for (int off = 1; off < 64; off <<= 1) s += __shfl_xor(s, off, 64);
  if ((tid & 63) == 0) red2[wv] = s;
  __syncthreads();
  if (tid == 0){
    float st = red2[0] + red2[1] + red2[2] + red2[3];
    part[bid*2]     = m;
    part[bid*2 + 1] = st;
  }
}

// ---------------- K7b: normalize in place (chunk combine fused in) ----------------
__global__ void sm_norm_kernel(float* __restrict__ logits, const float* __restrict__ part){
  int bid = blockIdx.x;
  int b = bid >> 3, ch = bid & 7;
  int base = b*32000 + ch*4000;
  int tid = threadIdx.x;
  float M = -INFINITY;
#pragma unroll
  for (int cc = 0; cc < 8; ++cc) M = fmaxf(M, part[(b*8 + cc)*2]);
  float S = 0.f;
#pragma unroll
  for (int cc = 0; cc < 8; ++cc) S += part[(b*8 + cc)*2 + 1] * __expf(part[(b*8 + cc)*2] - M);
  float inv = 1.0f / S;
#pragma unroll
  for (int i = 0; i < 16; ++i){
    int idx = i*256 + tid;
    if (idx < 4000){
      int o = base + idx;
      logits[o] = __expf(logits[o] - M) * inv;
    }
  }
}

extern "C" void kernel_launch(void* const* d_in, const int* in_sizes, int n_in,
                              void* d_out, int out_size, void* d_ws, size_t ws_size,
                              hipStream_t stream) {
  const float* inputs = (const float*)d_in[0];
  const float* stm    = (const float*)d_in[1];
  const float* xseq   = (const float*)d_in[2];
  const float* Va     = (const float*)d_in[3];
  const float* Wa     = (const float*)d_in[4];
  const float* Wr = (const float*)d_in[5];
  const float* Ur = (const float*)d_in[6];
  const float* Cr = (const float*)d_in[7];
  const float* br = (const float*)d_in[8];
  const float* Wz = (const float*)d_in[9];
  const float* Uz = (const float*)d_in[10];
  const float* Cz = (const float*)d_in[11];
  const float* bz = (const float*)d_in[12];
  const float* Wp = (const float*)d_in[13];
  const float* Up = (const float*)d_in[14];
  const float* Cp = (const float*)d_in[15];
  const float* bp = (const float*)d_in[16];
  const float* Wo = (const float*)d_in[17];
  const float* Uo = (const float*)d_in[18];
  const float* Co = (const float*)d_in[19];
  const float* bo = (const float*)d_in[20];

  float* out   = (float*)d_out;            // [64][32000] softmax output
  float* stout = out + (size_t)B_*O_;      // [64][256] new state

  float* wsf = (float*)d_ws;
  unsigned short* bpack = (unsigned short*)d_ws;     // 131072 ushorts = 65536 f-slots
  float* sp   = wsf + 65536;    // [64][512]
  float* et   = wsf + 98304;    // [64][2048]
  float* at   = wsf + 229376;   // [64][2048]
  float* cp   = wsf + 360448;   // [64][8][256]
  unsigned short* X1bf = (unsigned short*)(wsf + 491520);  // [64][768] bf16
  float* part = wsf + 516096;   // [512][2]
  float* rs   = wsf + 517120;   // [64][256]
  float* ztb  = wsf + 533504;   // [64][256]
  float* pic  = wsf + 549888;   // [64][256]

  pack_b_kernel<<<64, 256, 0, stream>>>(Wa, bpack);
  stmpart_mfma_kernel<<<8, 256, 0, stream>>>(stm, Wa, sp);
  et3_kernel<<<1024, 512, 0, stream>>>(xseq, bpack, Va, sp, et);
  at_kernel<<<64, 256, 0, stream>>>(et, at);
  ctxpart_kernel<<<dim3(8, 64), 256, 0, stream>>>(at, xseq, cp);
  ctx_x1_kernel<<<64, 256, 0, stream>>>(cp, inputs, stm, X1bf);
  gates1_kernel<<<12, 256, 0, stream>>>(X1bf, stm, Wr, Ur, Cr, br,
                                        Wz, Uz, Cz, bz, Wp, Cp, bp,
                                        rs, ztb, pic);
  gates2_kernel<<<4, 256, 0, stream>>>(rs, Up, pic, ztb, stm, stout);
  logits_mfma_kernel<<<500, 256, 0, stream>>>(X1bf, Wo, Uo, Co, bo, out);
  sm_part_kernel<<<512, 256, 0, stream>>>(out, part);
  sm_norm_kernel<<<512, 256, 0, stream>>>(out, part);
}

// Round 6
// 175.242 us; speedup vs baseline: 2.1145x; 2.1145x over previous
//
#include <hip/hip_runtime.h>
#include <hip/hip_bf16.h>

#define B_ 64
#define T_ 2048
#define E_ 256
#define U_ 256
#define O_ 32000
#define UE_ 512

typedef __attribute__((ext_vector_type(8))) short bf16x8;
typedef __attribute__((ext_vector_type(4))) float f32x4;

__device__ __forceinline__ unsigned short f2bf(float f){
  __hip_bfloat16 h = __float2bfloat16(f);
  return __builtin_bit_cast(unsigned short, h);
}
__device__ __forceinline__ unsigned pk2bf(float a, float b){
  return (unsigned)f2bf(a) | ((unsigned)f2bf(b) << 16);
}
__device__ __forceinline__ bf16x8 pack8(const float* v0, const float* v1){
  float4 x = *(const float4*)v0;
  float4 y = *(const float4*)v1;
  uint4 pk;
  pk.x = pk2bf(x.x, x.y); pk.y = pk2bf(x.z, x.w);
  pk.z = pk2bf(y.x, y.y); pk.w = pk2bf(y.z, y.w);
  return __builtin_bit_cast(bf16x8, pk);
}
__device__ __forceinline__ float ftanh(float x){
  float e = __expf(2.0f*x);
  return 1.0f - 2.0f/(e + 1.0f);
}
__device__ __forceinline__ float fsig(float x){
  return 1.0f/(1.0f + __expf(-x));
}

// ---------------- K0a: pack W_a[256:512, :] into bf16 MFMA-fragment layout ----------------
// bpack[((ks*4+g)*512 + n)*8 + i] = bf16( W_a[(256 + ks*32 + g*8 + i)*512 + n] )
__global__ void pack_b_kernel(const float* __restrict__ Wa, unsigned short* __restrict__ bpack){
  int idx = blockIdx.x*256 + threadIdx.x;      // 16384 = 32 ktg * 512 n
  int n = idx & 511;
  int ktg = idx >> 9;
  int erow = ktg * 8;
  unsigned short o[8];
#pragma unroll
  for (int i = 0; i < 8; ++i)
    o[i] = f2bf(Wa[(256 + erow + i)*512 + n]);
  uint4 v;
  v.x = (unsigned)o[0] | ((unsigned)o[1] << 16);
  v.y = (unsigned)o[2] | ((unsigned)o[3] << 16);
  v.z = (unsigned)o[4] | ((unsigned)o[5] << 16);
  v.w = (unsigned)o[6] | ((unsigned)o[7] << 16);
  ((uint4*)bpack)[idx] = v;
}

// ---------------- K0b (MFMA): sp[b][n] = sum_u stm[b][u] * W_a[u][n], n in [0,512) ----------------
__global__ __launch_bounds__(256)
void stmpart_mfma_kernel(const float* __restrict__ stm, const float* __restrict__ Wa,
                         float* __restrict__ sp){
  int tid = threadIdx.x;
  int w = tid >> 6, l = tid & 63, c = l & 15, g = l >> 4;
  int n0 = blockIdx.x*64 + w*16;        // 8 blocks -> 512 cols
  f32x4 zero = {0.f,0.f,0.f,0.f};
  f32x4 acc[4];
#pragma unroll
  for (int mt = 0; mt < 4; ++mt) acc[mt] = zero;
#pragma unroll
  for (int ks = 0; ks < 8; ++ks){
    int kg = ks*32 + 8*g;
    bf16x8 a[4];
#pragma unroll
    for (int mt = 0; mt < 4; ++mt){
      const float* ap = stm + (mt*16 + c)*256 + kg;
      a[mt] = pack8(ap, ap + 4);
    }
    const float* bpt = Wa + (size_t)kg*512 + n0 + c;
    float bv[8];
#pragma unroll
    for (int i = 0; i < 8; ++i) bv[i] = bpt[(size_t)i*512];
    uint4 pk;
    pk.x = pk2bf(bv[0], bv[1]); pk.y = pk2bf(bv[2], bv[3]);
    pk.z = pk2bf(bv[4], bv[5]); pk.w = pk2bf(bv[6], bv[7]);
    bf16x8 bfr = __builtin_bit_cast(bf16x8, pk);
#pragma unroll
    for (int mt = 0; mt < 4; ++mt)
      acc[mt] = __builtin_amdgcn_mfma_f32_16x16x32_bf16(a[mt], bfr, acc[mt], 0, 0, 0);
  }
#pragma unroll
  for (int mt = 0; mt < 4; ++mt)
#pragma unroll
    for (int r = 0; r < 4; ++r){
      int m = mt*16 + 4*g + r;
      sp[m*512 + n0 + c] = acc[mt][r];
    }
}

// ---------------- K1 v5: fused et GEMM (round-3 structure + swizzled frag-contiguous LDS) ----------------
// 2048 blocks x 512 threads, one 64-row x 512-col tile per block.
// LDS A-tile: uint4 slot s = (mt*8 + ks)*64 + g*16 + c holds A[mt*16+c][ks*32+8g .. +7],
// stored at physical slot s ^ ((s>>4)&7)  (conflict-free b128 reads, measured 0 in et2/et3).
__global__ __launch_bounds__(512, 4)
void et_kernel(const float* __restrict__ xseq, const unsigned short* __restrict__ bpack,
               const float* __restrict__ va, const float* __restrict__ sp,
               float* __restrict__ et){
  __shared__ __align__(16) uint4 sA4[2048];   // 32KB
  __shared__ float sVa[512];
  __shared__ float sSp[512];
  __shared__ float sEt[8][64];
  int tid = threadIdx.x;
  int m0 = blockIdx.x * 64;
  int b  = m0 >> 11;

  // stage A tile (64 rows x 256 k) fp32 -> bf16 LDS (frag-contiguous, swizzled)
  const float4* x4 = (const float4*)xseq + (size_t)m0 * 64;
  uint2* sA2 = (uint2*)sA4;
#pragma unroll
  for (int i = 0; i < 8; ++i){
    int p = i*512 + tid;
    int row = p >> 6, kq = p & 63;
    float4 v = x4[row*64 + kq];
    uint2 u;
    u.x = pk2bf(v.x, v.y);
    u.y = pk2bf(v.z, v.w);
    int s = ((row>>4)*8 + (kq>>3))*64 + ((kq>>1)&3)*16 + (row&15);
    sA2[(s ^ ((s>>4)&7))*2 + (kq&1)] = u;
  }
  sVa[tid < 512 ? tid : 0] = va[tid];
  sSp[tid] = sp[b*512 + tid];
  __syncthreads();

  int w = tid >> 6, l = tid & 63, c = l & 15, g = l >> 4;
  f32x4 zero = {0.f, 0.f, 0.f, 0.f};
  f32x4 acc[4][4];
#pragma unroll
  for (int mt = 0; mt < 4; ++mt)
#pragma unroll
    for (int nt = 0; nt < 4; ++nt) acc[mt][nt] = zero;

  const bf16x8* bp = (const bf16x8*)bpack;
#pragma unroll
  for (int ks = 0; ks < 8; ++ks){
    bf16x8 a[4], bb[4];
#pragma unroll
    for (int mt = 0; mt < 4; ++mt){
      int idx = (mt*8 + ks)*64 + l;
      a[mt] = *(const bf16x8*)&sA4[idx ^ ((idx>>4)&7)];
    }
    int bbase = (ks*4 + g)*512 + w*64 + c;
#pragma unroll
    for (int nt = 0; nt < 4; ++nt)
      bb[nt] = bp[bbase + nt*16];
#pragma unroll
    for (int mt = 0; mt < 4; ++mt)
#pragma unroll
      for (int nt = 0; nt < 4; ++nt)
        acc[mt][nt] = __builtin_amdgcn_mfma_f32_16x16x32_bf16(a[mt], bb[nt], acc[mt][nt], 0, 0, 0);
  }

  float pr[4][4];
#pragma unroll
  for (int mt = 0; mt < 4; ++mt)
#pragma unroll
    for (int r = 0; r < 4; ++r){
      float p = 0.f;
#pragma unroll
      for (int nt = 0; nt < 4; ++nt){
        int n = w*64 + nt*16 + c;
        float v = acc[mt][nt][r] + sSp[n];
        p += sVa[n] * ftanh(v);
      }
      pr[mt][r] = p;
    }
#pragma unroll
  for (int mask = 1; mask < 16; mask <<= 1){
#pragma unroll
    for (int mt = 0; mt < 4; ++mt)
#pragma unroll
      for (int r = 0; r < 4; ++r)
        pr[mt][r] += __shfl_xor(pr[mt][r], mask, 64);
  }
  if (c == 0){
#pragma unroll
    for (int mt = 0; mt < 4; ++mt)
#pragma unroll
      for (int r = 0; r < 4; ++r)
        sEt[w][mt*16 + 4*g + r] = pr[mt][r];
  }
  __syncthreads();
  if (tid < 64){
    float e = 0.f;
#pragma unroll
    for (int ww = 0; ww < 8; ++ww) e += sEt[ww][tid];
    et[m0 + tid] = e;
  }
}

// ---------------- K2: softmax over T per b -> at ----------------
__global__ void at_kernel(const float* __restrict__ et, float* __restrict__ at){
  __shared__ float red[4];
  __shared__ float red2[4];
  int b = blockIdx.x, tid = threadIdx.x;
  float v[8];
#pragma unroll
  for (int i = 0; i < 8; ++i) v[i] = et[b*2048 + i*256 + tid];
  float m = v[0];
#pragma unroll
  for (int i = 1; i < 8; ++i) m = fmaxf(m, v[i]);
#pragma unroll
  for (int off = 1; off < 64; off <<= 1) m = fmaxf(m, __shfl_xor(m, off, 64));
  int wv = tid >> 6;
  if ((tid & 63) == 0) red[wv] = m;
  __syncthreads();
  m = fmaxf(fmaxf(red[0], red[1]), fmaxf(red[2], red[3]));
  float e[8]; float s = 0.f;
#pragma unroll
  for (int i = 0; i < 8; ++i){ e[i] = __expf(v[i] - m); s += e[i]; }
#pragma unroll
  for (int off = 1; off < 64; off <<= 1) s += __shfl_xor(s, off, 64);
  if ((tid & 63) == 0) red2[wv] = s;
  __syncthreads();
  s = red2[0] + red2[1] + red2[2] + red2[3];
  float inv = 1.0f / s;
#pragma unroll
  for (int i = 0; i < 8; ++i) at[b*2048 + i*256 + tid] = e[i] * inv;
}

// ---------------- K3: context partials over T chunks ----------------
__global__ void ctxpart_kernel(const float* __restrict__ at, const float* __restrict__ xseq,
                               float* __restrict__ cp){
  __shared__ float s_at[256];
  int ch = blockIdx.x;
  int b  = blockIdx.y;
  int e  = threadIdx.x;
  int t0 = ch * 256;
  s_at[e] = at[b*2048 + t0 + e];
  __syncthreads();
  float acc = 0.f;
  const float* xp = xseq + ((size_t)(b*2048 + t0))*256 + e;
#pragma unroll 4
  for (int tt = 0; tt < 256; ++tt)
    acc += s_at[tt] * xp[(size_t)tt * 256];
  cp[(b*8 + ch)*256 + e] = acc;
}

// ---------------- K4: reduce context + build X1bf = bf16([inputs | stm | ctx]) ----------------
__global__ void ctx_x1_kernel(const float* __restrict__ cp, const float* __restrict__ inputs,
                              const float* __restrict__ stm,
                              unsigned short* __restrict__ X1bf){
  int b = blockIdx.x, e = threadIdx.x;
  float s = 0.f;
#pragma unroll
  for (int c = 0; c < 8; ++c) s += cp[(b*8 + c)*256 + e];
  X1bf[b*768 + e]        = f2bf(inputs[b*256 + e]);
  X1bf[b*768 + 256 + e]  = f2bf(stm[b*256 + e]);
  X1bf[b*768 + 512 + e]  = f2bf(s);
}

// ---------------- K5a: gate preactivations r,z + p_ic via MFMA ----------------
__global__ __launch_bounds__(256)
void gates1_kernel(const unsigned short* __restrict__ X1bf, const float* __restrict__ stm,
                   const float* __restrict__ Wr, const float* __restrict__ Ur,
                   const float* __restrict__ Cr, const float* __restrict__ brr,
                   const float* __restrict__ Wz, const float* __restrict__ Uz,
                   const float* __restrict__ Cz, const float* __restrict__ bzz,
                   const float* __restrict__ Wp, const float* __restrict__ Cp,
                   const float* __restrict__ bpp,
                   float* __restrict__ rs, float* __restrict__ ztb, float* __restrict__ pic){
  int tid = threadIdx.x;
  int w = tid >> 6, l = tid & 63, c = l & 15, g = l >> 4;
  int n0 = blockIdx.x*64 + w*16;          // 12 blocks -> 768 cols
  int gate = n0 >> 8;
  int col0 = n0 & 255;
  const float* W0; const float* W1; const float* W2; const float* bias;
  if (gate == 0){ W0 = Wr; W1 = Ur; W2 = Cr; bias = brr; }
  else if (gate == 1){ W0 = Wz; W1 = Uz; W2 = Cz; bias = bzz; }
  else { W0 = Wp; W1 = nullptr; W2 = Cp; bias = bpp; }

  f32x4 zero = {0.f,0.f,0.f,0.f};
  f32x4 acc[4];
#pragma unroll
  for (int mt = 0; mt < 4; ++mt) acc[mt] = zero;

#pragma unroll
  for (int ph = 0; ph < 3; ++ph){
    const float* src = (ph == 0) ? W0 : (ph == 1) ? W1 : W2;
    if (src == nullptr) continue;
#pragma unroll
    for (int ks = 0; ks < 8; ++ks){
      int kg = ks*32 + 8*g;
      bf16x8 a[4];
#pragma unroll
      for (int mt = 0; mt < 4; ++mt)
        a[mt] = *(const bf16x8*)&X1bf[(mt*16 + c)*768 + ph*256 + kg];
      const float* bpt = src + (size_t)kg*256 + col0 + c;
      float bv[8];
#pragma unroll
      for (int i = 0; i < 8; ++i) bv[i] = bpt[(size_t)i*256];
      uint4 pk;
      pk.x = pk2bf(bv[0], bv[1]); pk.y = pk2bf(bv[2], bv[3]);
      pk.z = pk2bf(bv[4], bv[5]); pk.w = pk2bf(bv[6], bv[7]);
      bf16x8 bfr = __builtin_bit_cast(bf16x8, pk);
#pragma unroll
      for (int mt = 0; mt < 4; ++mt)
        acc[mt] = __builtin_amdgcn_mfma_f32_16x16x32_bf16(a[mt], bfr, acc[mt], 0, 0, 0);
    }
  }

  int n = col0 + c;
  float bi = bias[n];
#pragma unroll
  for (int mt = 0; mt < 4; ++mt)
#pragma unroll
    for (int r = 0; r < 4; ++r){
      int m = mt*16 + 4*g + r;
      float pre = acc[mt][r] + bi;
      if (gate == 0)      rs[m*256 + n]  = fsig(pre) * stm[m*256 + n];
      else if (gate == 1) ztb[m*256 + n] = fsig(pre);
      else                pic[m*256 + n] = pre;
    }
}

// ---------------- K5b: st = (1-z)*stm + z*tanh(pic + rs@Up) ----------------
__global__ __launch_bounds__(256)
void gates2_kernel(const float* __restrict__ rs, const float* __restrict__ Up,
                   const float* __restrict__ pic, const float* __restrict__ ztb,
                   const float* __restrict__ stm, float* __restrict__ stout){
  int tid = threadIdx.x;
  int w = tid >> 6, l = tid & 63, c = l & 15, g = l >> 4;
  int n0 = blockIdx.x*64 + w*16;          // 4 blocks -> 256 cols
  f32x4 zero = {0.f,0.f,0.f,0.f};
  f32x4 acc[4];
#pragma unroll
  for (int mt = 0; mt < 4; ++mt) acc[mt] = zero;
#pragma unroll
  for (int ks = 0; ks < 8; ++ks){
    int kg = ks*32 + 8*g;
    bf16x8 a[4];
#pragma unroll
    for (int mt = 0; mt < 4; ++mt){
      const float* ap = rs + (mt*16 + c)*256 + kg;
      a[mt] = pack8(ap, ap + 4);
    }
    const float* bpt = Up + (size_t)kg*256 + n0 + c;
    float bv[8];
#pragma unroll
    for (int i = 0; i < 8; ++i) bv[i] = bpt[(size_t)i*256];
    uint4 pk;
    pk.x = pk2bf(bv[0], bv[1]); pk.y = pk2bf(bv[2], bv[3]);
    pk.z = pk2bf(bv[4], bv[5]); pk.w = pk2bf(bv[6], bv[7]);
    bf16x8 bfr = __builtin_bit_cast(bf16x8, pk);
#pragma unroll
    for (int mt = 0; mt < 4; ++mt)
      acc[mt] = __builtin_amdgcn_mfma_f32_16x16x32_bf16(a[mt], bfr, acc[mt], 0, 0, 0);
  }
#pragma unroll
  for (int mt = 0; mt < 4; ++mt)
#pragma unroll
    for (int r = 0; r < 4; ++r){
      int m = mt*16 + 4*g + r;
      int o = m*256 + n0 + c;
      float ap = pic[o] + acc[mt][r];
      float z = ztb[o];
      stout[o] = (1.f - z)*stm[o] + z*ftanh(ap);
    }
}

// ---------------- K6: logits via MFMA, weights converted fp32->bf16 on the fly ----------------
__global__ __launch_bounds__(256)
void logits_mfma_kernel(const unsigned short* __restrict__ X1bf,
                        const float* __restrict__ Wo, const float* __restrict__ Uo,
                        const float* __restrict__ Co, const float* __restrict__ boo,
                        float* __restrict__ outl){
  int tid = threadIdx.x;
  int w = tid >> 6, l = tid & 63, c = l & 15, g = l >> 4;
  int n0 = blockIdx.x*64 + w*16;
  f32x4 zero = {0.f,0.f,0.f,0.f};
  f32x4 acc[4];
#pragma unroll
  for (int mt = 0; mt < 4; ++mt) acc[mt] = zero;

#pragma unroll
  for (int ph = 0; ph < 3; ++ph){
    const float* src = (ph == 0) ? Wo : (ph == 1) ? Uo : Co;
#pragma unroll 2
    for (int ks = 0; ks < 8; ++ks){
      int kg = ph*256 + ks*32 + 8*g;
      bf16x8 a[4];
#pragma unroll
      for (int mt = 0; mt < 4; ++mt)
        a[mt] = *(const bf16x8*)&X1bf[(mt*16 + c)*768 + kg];
      const float* bpt = src + (size_t)(ks*32 + 8*g)*32000 + n0 + c;
      float bv[8];
#pragma unroll
      for (int i = 0; i < 8; ++i) bv[i] = bpt[(size_t)i*32000];
      uint4 pk;
      pk.x = pk2bf(bv[0], bv[1]);
      pk.y = pk2bf(bv[2], bv[3]);
      pk.z = pk2bf(bv[4], bv[5]);
      pk.w = pk2bf(bv[6], bv[7]);
      bf16x8 bfr = __builtin_bit_cast(bf16x8, pk);
#pragma unroll
      for (int mt = 0; mt < 4; ++mt)
        acc[mt] = __builtin_amdgcn_mfma_f32_16x16x32_bf16(a[mt], bfr, acc[mt], 0, 0, 0);
    }
  }

  float bias = boo[n0 + c];
#pragma unroll
  for (int mt = 0; mt < 4; ++mt)
#pragma unroll
    for (int r = 0; r < 4; ++r){
      int m = mt*16 + 4*g + r;
      outl[(size_t)m*32000 + n0 + c] = acc[mt][r] + bias;
    }
}

// ---------------- K7a: per-(b,chunk) (max, sumexp) partials ----------------
__global__ void sm_part_kernel(const float* __restrict__ logits, float* __restrict__ part){
  __shared__ float red[4];
  __shared__ float red2[4];
  int bid = blockIdx.x;           // 512 = 64 b * 8 chunks
  int b = bid >> 3, ch = bid & 7;
  int base = b*32000 + ch*4000;
  int tid = threadIdx.x;
  float v[16];
#pragma unroll
  for (int i = 0; i < 16; ++i){
    int idx = i*256 + tid;
    v[i] = (idx < 4000) ? logits[base + idx] : -INFINITY;
  }
  float m = v[0];
#pragma unroll
  for (int i = 1; i < 16; ++i) m = fmaxf(m, v[i]);
#pragma unroll
  for (int off = 1; off < 64; off <<= 1) m = fmaxf(m, __shfl_xor(m, off, 64));
  int wv = tid >> 6;
  if ((tid & 63) == 0) red[wv] = m;
  __syncthreads();
  m = fmaxf(fmaxf(red[0], red[1]), fmaxf(red[2], red[3]));
  float s = 0.f;
#pragma unroll
  for (int i = 0; i < 16; ++i) s += __expf(v[i] - m);
#pragma unroll
  for (int off = 1; off < 64; off <<= 1) s += __shfl_xor(s, off, 64);
  if ((tid & 63) == 0) red2[wv] = s;
  __syncthreads();
  if (tid == 0){
    float st = red2[0] + red2[1] + red2[2] + red2[3];
    part[bid*2]     = m;
    part[bid*2 + 1] = st;
  }
}

// ---------------- K7b: normalize in place (chunk combine fused in) ----------------
__global__ void sm_norm_kernel(float* __restrict__ logits, const float* __restrict__ part){
  int bid = blockIdx.x;
  int b = bid >> 3, ch = bid & 7;
  int base = b*32000 + ch*4000;
  int tid = threadIdx.x;
  float M = -INFINITY;
#pragma unroll
  for (int cc = 0; cc < 8; ++cc) M = fmaxf(M, part[(b*8 + cc)*2]);
  float S = 0.f;
#pragma unroll
  for (int cc = 0; cc < 8; ++cc) S += part[(b*8 + cc)*2 + 1] * __expf(part[(b*8 + cc)*2] - M);
  float inv = 1.0f / S;
#pragma unroll
  for (int i = 0; i < 16; ++i){
    int idx = i*256 + tid;
    if (idx < 4000){
      int o = base + idx;
      logits[o] = __expf(logits[o] - M) * inv;
    }
  }
}

extern "C" void kernel_launch(void* const* d_in, const int* in_sizes, int n_in,
                              void* d_out, int out_size, void* d_ws, size_t ws_size,
                              hipStream_t stream) {
  const float* inputs = (const float*)d_in[0];
  const float* stm    = (const float*)d_in[1];
  const float* xseq   = (const float*)d_in[2];
  const float* Va     = (const float*)d_in[3];
  const float* Wa     = (const float*)d_in[4];
  const float* Wr = (const float*)d_in[5];
  const float* Ur = (const float*)d_in[6];
  const float* Cr = (const float*)d_in[7];
  const float* br = (const float*)d_in[8];
  const float* Wz = (const float*)d_in[9];
  const float* Uz = (const float*)d_in[10];
  const float* Cz = (const float*)d_in[11];
  const float* bz = (const float*)d_in[12];
  const float* Wp = (const float*)d_in[13];
  const float* Up = (const float*)d_in[14];
  const float* Cp = (const float*)d_in[15];
  const float* bp = (const float*)d_in[16];
  const float* Wo = (const float*)d_in[17];
  const float* Uo = (const float*)d_in[18];
  const float* Co = (const float*)d_in[19];
  const float* bo = (const float*)d_in[20];

  float* out   = (float*)d_out;            // [64][32000] softmax output
  float* stout = out + (size_t)B_*O_;      // [64][256] new state

  float* wsf = (float*)d_ws;
  unsigned short* bpack = (unsigned short*)d_ws;     // 131072 ushorts = 65536 f-slots
  float* sp   = wsf + 65536;    // [64][512]
  float* et   = wsf + 98304;    // [64][2048]
  float* at   = wsf + 229376;   // [64][2048]
  float* cp   = wsf + 360448;   // [64][8][256]
  unsigned short* X1bf = (unsigned short*)(wsf + 491520);  // [64][768] bf16
  float* part = wsf + 516096;   // [512][2]
  float* rs   = wsf + 517120;   // [64][256]
  float* ztb  = wsf + 533504;   // [64][256]
  float* pic  = wsf + 549888;   // [64][256]

  pack_b_kernel<<<64, 256, 0, stream>>>(Wa, bpack);
  stmpart_mfma_kernel<<<8, 256, 0, stream>>>(stm, Wa, sp);
  et_kernel<<<2048, 512, 0, stream>>>(xseq, bpack, Va, sp, et);
  at_kernel<<<64, 256, 0, stream>>>(et, at);
  ctxpart_kernel<<<dim3(8, 64), 256, 0, stream>>>(at, xseq, cp);
  ctx_x1_kernel<<<64, 256, 0, stream>>>(cp, inputs, stm, X1bf);
  gates1_kernel<<<12, 256, 0, stream>>>(X1bf, stm, Wr, Ur, Cr, br,
                                        Wz, Uz, Cz, bz, Wp, Cp, bp,
                                        rs, ztb, pic);
  gates2_kernel<<<4, 256, 0, stream>>>(rs, Up, pic, ztb, stm, stout);
  logits_mfma_kernel<<<500, 256, 0, stream>>>(X1bf, Wo, Uo, Co, bo, out);
  sm_part_kernel<<<512, 256, 0, stream>>>(out, part);
  sm_norm_kernel<<<512, 256, 0, stream>>>(out, part);
}